// Round 1
// baseline (633.904 us; speedup 1.0000x reference)
//
#include <hip/hip_runtime.h>
#include <hip/hip_bf16.h>
#include <cstdint>
#include <cstddef>

#define B_ 128
#define D_ 1024
#define GEN_V_ 50000
#define OUT_V_ 50257
#define S_ 512

#define NTILE 64
#define NBLK 782         // ceil(GEN_V/NTILE)
#define BK 64
#define LD 72            // padded k-stride (shorts); 36-dword row stride

typedef __attribute__((ext_vector_type(8))) short bf16x8;
typedef __attribute__((ext_vector_type(8))) unsigned short u16x8;
typedef __attribute__((ext_vector_type(4))) float f32x4;

__device__ __forceinline__ unsigned short f2bf(float f) {
  unsigned u = __float_as_uint(f);
  u += 0x7fffu + ((u >> 16) & 1u);   // RNE
  return (unsigned short)(u >> 16);
}

// ---------------- gate: interp[b] = sigmoid(x[b,:]·W_gate + b_gate) ----------------
__global__ void gate_kernel(const float* __restrict__ x, const float* __restrict__ Wg,
                            const float* __restrict__ bg, float* __restrict__ interp) {
  int b = blockIdx.x;
  int t = threadIdx.x;  // 256
  const float4* xr = (const float4*)(x + (size_t)b * D_);
  const float4* wr = (const float4*)Wg;
  float s = 0.f;
  for (int i = t; i < D_ / 4; i += 256) {
    float4 xv = xr[i], wv = wr[i];
    s += xv.x * wv.x + xv.y * wv.y + xv.z * wv.z + xv.w * wv.w;
  }
  for (int o = 32; o > 0; o >>= 1) s += __shfl_down(s, o);
  __shared__ float red[4];
  int lane = t & 63, w = t >> 6;
  if (lane == 0) red[w] = s;
  __syncthreads();
  if (t == 0) {
    float tot = red[0] + red[1] + red[2] + red[3] + bg[0];
    interp[b] = 1.f / (1.f + __expf(-tot));
  }
}

// ---------------- GEMM + fused exp + atomic scatter into out + row partial sums ----
// e[b][v] = exp(x@W_gen + b_gen); atomicAdd(out[b][g2o[v]], e) (unscaled; normalized
// later by scale_kernel);  rowpart[row][blk] = sum over this block's cols.
// Block: 512 threads (8 waves, 2(M)x4(N)), tile M=128 x N=64, BK=64.
__global__ __launch_bounds__(512, 4) void gemm_scatter_kernel(
    const float* __restrict__ x, const float* __restrict__ W,
    const float* __restrict__ bgen, const int* __restrict__ g2o,
    float* __restrict__ out, float* __restrict__ rowpart) {
  __shared__ unsigned short sA[B_][LD];     // [m][k] bf16
  __shared__ unsigned short sB[NTILE][LD];  // [n][k] bf16 (k-packed stores: conflict-free)
  __shared__ float srow[B_];
  int tid = threadIdx.x;
  int lane = tid & 63;
  int wv = tid >> 6;            // 0..7
  int wm = wv & 1;              // m half (64)
  int wn = wv >> 1;             // n quarter (16)
  int nbase = blockIdx.x * NTILE;
  int l15 = lane & 15;
  int quad = lane >> 4;
  int koff0 = quad * 8;

  f32x4 acc[4];
#pragma unroll
  for (int i = 0; i < 4; i++) acc[i] = (f32x4){0.f, 0.f, 0.f, 0.f};

  // B staging assignment: each thread owns one (n, k-chunk): n=tid&63, kc=tid>>6 (0..7)
  int bn = lane;                // == tid & 63
  int kc = wv;                  // == tid >> 6
  bool colv = (nbase + bn) < GEN_V_;
  const float* Wcol = W + (size_t)kc * 8 * GEN_V_ + nbase + bn;

  const float4* xg = (const float4*)x;

  for (int k0 = 0; k0 < D_; k0 += BK) {
    // ---- stage A: x[0:128, k0:+64] fp32 -> bf16, [m][k] (coalesced 256B rows) ----
    int kb4 = k0 >> 2;
#pragma unroll
    for (int i = 0; i < 4; i++) {
      int q = tid + i * 512;          // 0..2047
      int m = q >> 4, c4 = q & 15;    // 16 float4 per 64-k row
      float4 v = xg[(size_t)m * (D_ / 4) + kb4 + c4];
      ushort4 h;
      h.x = f2bf(v.x); h.y = f2bf(v.y); h.z = f2bf(v.z); h.w = f2bf(v.w);
      *(ushort4*)&sA[m][c4 * 4] = h;
    }
    // ---- stage B: W[k0:+64, nbase:+64] -> bf16 [n][k], one 16B k-packed store ----
    {
      const float* Wp = Wcol + (size_t)k0 * GEN_V_;
      u16x8 hh;
#pragma unroll
      for (int j = 0; j < 8; j++) {
        float w = colv ? Wp[(size_t)j * GEN_V_] : 0.f;
        hh[j] = f2bf(w);
      }
      *(u16x8*)&sB[bn][kc * 8] = hh;   // dword stride 36/row: 8-lane groups cover 32 banks
    }
    __syncthreads();
    // ---- MFMA: wave tile 64(M) x 16(N) ----
#pragma unroll
    for (int ks = 0; ks < BK; ks += 32) {
      int koff = ks + koff0;
      bf16x8 bfr = *(const bf16x8*)&sB[wn * 16 + l15][koff];
      bf16x8 af[4];
#pragma unroll
      for (int mt = 0; mt < 4; mt++)
        af[mt] = *(const bf16x8*)&sA[wm * 64 + mt * 16 + l15][koff];
#pragma unroll
      for (int mt = 0; mt < 4; mt++)
        acc[mt] = __builtin_amdgcn_mfma_f32_16x16x32_bf16(af[mt], bfr, acc[mt], 0, 0, 0);
    }
    __syncthreads();
  }

  // ---- epilogue: e = exp(acc + bias); atomic scatter into out; row partial sums ----
  if (tid < B_) srow[tid] = 0.f;
  __syncthreads();
  int cg = nbase + wn * 16 + l15;
  bool cv = cg < GEN_V_;
  float bgv = cv ? bgen[cg] : 0.f;
  int og = cv ? g2o[cg] : 0;      // output-vocab target for this gen column
  int rquad = quad * 4;
#pragma unroll
  for (int mt = 0; mt < 4; mt++) {
    int rb = wm * 64 + mt * 16 + rquad;
#pragma unroll
    for (int r = 0; r < 4; r++) {
      float e = __expf(acc[mt][r] + bgv);   // logits in ±~5: no max-sub needed
      float contrib = cv ? e : 0.f;
      if (cv) atomicAdd(&out[(size_t)(rb + r) * OUT_V_ + og], e);
      // reduce across the 16 lanes sharing this row (stays within quad)
#pragma unroll
      for (int o = 1; o < 16; o <<= 1) contrib += __shfl_xor(contrib, o);
      if (l15 == 0) atomicAdd(&srow[rb + r], contrib);
    }
  }
  __syncthreads();
  if (tid < B_) rowpart[(size_t)tid * NBLK + blockIdx.x] = srow[tid];
}

// ---------------- row sums -> rowscale[b] = interp[b] / sum_b ----------------
__global__ void rowsum_kernel(const float* __restrict__ rowpart, const float* __restrict__ interp,
                              float* __restrict__ rowscale) {
  int b = blockIdx.x, t = threadIdx.x;  // 128 blocks x 256
  const float* rp = rowpart + (size_t)b * NBLK;
  float s = 0.f;
  for (int i = t; i < NBLK; i += 256) s += rp[i];
  for (int o = 32; o > 0; o >>= 1) s += __shfl_down(s, o);
  __shared__ float red[4];
  int lane = t & 63, w = t >> 6;
  if (lane == 0) red[w] = s;
  __syncthreads();
  if (t == 0) rowscale[b] = interp[b] / (red[0] + red[1] + red[2] + red[3]);
}

// ---------------- scale: out[b, :] *= rowscale[b]  (flat float4 over B*OUT_V) ------
#define NFLT4 ((B_ * OUT_V_) / 4)     // 6,432,896 floats -> 1,608,224 float4 (exact)
__global__ void scale_kernel(float* __restrict__ out, const float* __restrict__ rowscale) {
  unsigned i4 = blockIdx.x * 256u + threadIdx.x;
  if (i4 < (unsigned)NFLT4) {
    float4 v = ((float4*)out)[i4];
    unsigned e = i4 * 4u;
    unsigned b0 = e / OUT_V_;
    unsigned b3 = (e + 3u) / OUT_V_;
    if (b0 == b3) {
      float sc = rowscale[b0];
      v.x *= sc; v.y *= sc; v.z *= sc; v.w *= sc;
    } else {
      v.x *= rowscale[e / OUT_V_];
      v.y *= rowscale[(e + 1u) / OUT_V_];
      v.z *= rowscale[(e + 2u) / OUT_V_];
      v.w *= rowscale[(e + 3u) / OUT_V_];
    }
    ((float4*)out)[i4] = v;
  }
}

// ---------------- ptr scatter: out[b, i2o[ctx[b,s]]] += (1-interp_b) * alphas[b,s] --
__global__ void scatter_ptr_kernel(const float* __restrict__ alphas, const int* __restrict__ ctx,
                                   const int* __restrict__ i2o, const float* __restrict__ interp,
                                   float* __restrict__ out) {
  int b = blockIdx.x, s = threadIdx.x;  // 512 threads
  float w = 1.f - interp[b];
  int o = i2o[ctx[b * S_ + s]];
  atomicAdd(&out[(size_t)b * OUT_V_ + o], w * alphas[b * S_ + s]);
}

extern "C" void kernel_launch(void* const* d_in, const int* in_sizes, int n_in,
                              void* d_out, int out_size, void* d_ws, size_t ws_size,
                              hipStream_t stream) {
  const float* x      = (const float*)d_in[0];
  const float* alphas = (const float*)d_in[1];
  const float* Wg     = (const float*)d_in[2];
  const float* bg     = (const float*)d_in[3];
  const float* Wgen   = (const float*)d_in[4];
  const float* bgen   = (const float*)d_in[5];
  const int*   ctx    = (const int*)d_in[6];
  const int*   g2o    = (const int*)d_in[7];
  const int*   i2o    = (const int*)d_in[8];
  float* out = (float*)d_out;

  // workspace layout (4B elems): interp[128] | rowscale[128] | rowpart[128*NBLK]
  float* interp   = (float*)d_ws;
  float* rowscale = interp + B_;
  float* rowpart  = rowscale + B_;

  // out accumulates unscaled exp() via atomics -> must start at zero
  hipMemsetAsync(out, 0, (size_t)B_ * OUT_V_ * sizeof(float), stream);

  gate_kernel<<<B_, 256, 0, stream>>>(x, Wg, bg, interp);
  gemm_scatter_kernel<<<NBLK, 512, 0, stream>>>(x, Wgen, bgen, g2o, out, rowpart);
  rowsum_kernel<<<B_, 256, 0, stream>>>(rowpart, interp, rowscale);
  scale_kernel<<<(NFLT4 + 255) / 256, 256, 0, stream>>>(out, rowscale);
  scatter_ptr_kernel<<<B_, S_, 0, stream>>>(alphas, ctx, i2o, interp, out);
}

// Round 2
// 406.569 us; speedup vs baseline: 1.5592x; 1.5592x over previous
//
#include <hip/hip_runtime.h>
#include <hip/hip_bf16.h>
#include <cstdint>
#include <cstddef>

#define B_ 128
#define D_ 1024
#define GEN_V_ 50000
#define OUT_V_ 50257
#define S_ 512

#define NTILE 64
#define NBLK 782         // ceil(GEN_V/NTILE)
#define BK 64
#define LD 72            // padded k-stride (shorts); 36-dword row stride
#define CAP 8            // bucket capacity for inverted index (Poisson lambda~1)

typedef __attribute__((ext_vector_type(8))) short bf16x8;
typedef __attribute__((ext_vector_type(8))) unsigned short u16x8;
typedef __attribute__((ext_vector_type(4))) float f32x4;

__device__ __forceinline__ unsigned short f2bf(float f) {
  unsigned u = __float_as_uint(f);
  u += 0x7fffu + ((u >> 16) & 1u);   // RNE
  return (unsigned short)(u >> 16);
}

// ---------------- GEMM + fused exp + row partial sums -----------------------------
// elog[b][v] = exp(x@W_gen + b_gen);  rowpart[row][blk] = sum over this block's cols.
// Block: 512 threads (8 waves, 2(M)x4(N)), tile M=128 x N=64, BK=64.
__global__ __launch_bounds__(512, 4) void gemm_kernel(
    const float* __restrict__ x, const float* __restrict__ W,
    const float* __restrict__ bgen, float* __restrict__ elog,
    float* __restrict__ rowpart) {
  __shared__ unsigned short sA[B_][LD];     // [m][k] bf16
  __shared__ unsigned short sB[NTILE][LD];  // [n][k] bf16 (k-packed stores: conflict-free)
  __shared__ float srow[B_];
  int tid = threadIdx.x;
  int lane = tid & 63;
  int wv = tid >> 6;            // 0..7
  int wm = wv & 1;              // m half (64)
  int wn = wv >> 1;             // n quarter (16)
  int nbase = blockIdx.x * NTILE;
  int l15 = lane & 15;
  int quad = lane >> 4;
  int koff0 = quad * 8;

  f32x4 acc[4];
#pragma unroll
  for (int i = 0; i < 4; i++) acc[i] = (f32x4){0.f, 0.f, 0.f, 0.f};

  // B staging assignment: each thread owns one (n, k-chunk): n=tid&63, kc=tid>>6 (0..7)
  int bn = lane;                // == tid & 63
  int kc = wv;                  // == tid >> 6
  bool colv = (nbase + bn) < GEN_V_;
  const float* Wcol = W + (size_t)kc * 8 * GEN_V_ + nbase + bn;

  const float4* xg = (const float4*)x;

  for (int k0 = 0; k0 < D_; k0 += BK) {
    // ---- stage A: x[0:128, k0:+64] fp32 -> bf16, [m][k] (coalesced 256B rows) ----
    int kb4 = k0 >> 2;
#pragma unroll
    for (int i = 0; i < 4; i++) {
      int q = tid + i * 512;          // 0..2047
      int m = q >> 4, c4 = q & 15;    // 16 float4 per 64-k row
      float4 v = xg[(size_t)m * (D_ / 4) + kb4 + c4];
      ushort4 h;
      h.x = f2bf(v.x); h.y = f2bf(v.y); h.z = f2bf(v.z); h.w = f2bf(v.w);
      *(ushort4*)&sA[m][c4 * 4] = h;
    }
    // ---- stage B: W[k0:+64, nbase:+64] -> bf16 [n][k], one 16B k-packed store ----
    {
      const float* Wp = Wcol + (size_t)k0 * GEN_V_;
      u16x8 hh;
#pragma unroll
      for (int j = 0; j < 8; j++) {
        float w = colv ? Wp[(size_t)j * GEN_V_] : 0.f;
        hh[j] = f2bf(w);
      }
      *(u16x8*)&sB[bn][kc * 8] = hh;   // dword stride 36/row: 8-lane groups cover 32 banks
    }
    __syncthreads();
    // ---- MFMA: wave tile 64(M) x 16(N) ----
#pragma unroll
    for (int ks = 0; ks < BK; ks += 32) {
      int koff = ks + koff0;
      bf16x8 bfr = *(const bf16x8*)&sB[wn * 16 + l15][koff];
      bf16x8 af[4];
#pragma unroll
      for (int mt = 0; mt < 4; mt++)
        af[mt] = *(const bf16x8*)&sA[wm * 64 + mt * 16 + l15][koff];
#pragma unroll
      for (int mt = 0; mt < 4; mt++)
        acc[mt] = __builtin_amdgcn_mfma_f32_16x16x32_bf16(af[mt], bfr, acc[mt], 0, 0, 0);
    }
    __syncthreads();
  }

  // ---- epilogue: e = exp(acc + bias); store elog; per-row partial sums ----
  if (tid < B_) srow[tid] = 0.f;
  __syncthreads();
  int cg = nbase + wn * 16 + l15;
  bool cv = cg < GEN_V_;
  float bgv = cv ? bgen[cg] : 0.f;
  int rquad = quad * 4;
#pragma unroll
  for (int mt = 0; mt < 4; mt++) {
    int rb = wm * 64 + mt * 16 + rquad;
#pragma unroll
    for (int r = 0; r < 4; r++) {
      float e = __expf(acc[mt][r] + bgv);   // logits in ±~5: no max-sub needed
      float contrib = cv ? e : 0.f;
      if (cv) elog[(size_t)(rb + r) * GEN_V_ + cg] = e;
      // reduce across the 16 lanes sharing this row (stays within quad)
#pragma unroll
      for (int o = 1; o < 16; o <<= 1) contrib += __shfl_xor(contrib, o);
      if (l15 == 0) atomicAdd(&srow[rb + r], contrib);
    }
  }
  __syncthreads();
  if (tid < B_) rowpart[(size_t)tid * NBLK + blockIdx.x] = srow[tid];
}

// ------------- inverted index of g2o: fixed-cap buckets + overflow list -------------
// cnt[o] counts hits; first CAP go to vlist[o*CAP+slot]; excess -> (o,v) overflow pairs.
__global__ void build_index_kernel(const int* __restrict__ g2o, int* __restrict__ cnt,
                                   int* __restrict__ vlist, int* __restrict__ novf,
                                   int* __restrict__ ovf) {
  int v = blockIdx.x * 256 + threadIdx.x;
  if (v < GEN_V_) {
    int o = g2o[v];
    int slot = atomicAdd(&cnt[o], 1);
    if (slot < CAP) {
      vlist[o * CAP + slot] = v;
    } else {
      int i = atomicAdd(novf, 1);
      ovf[2 * i] = o;
      ovf[2 * i + 1] = v;
    }
  }
}

// ------------- rowsum + gate fused: rowscale[b] = sigmoid(x·Wg+bg) / sum_b ---------
__global__ void rowsum_gate_kernel(const float* __restrict__ rowpart,
                                   const float* __restrict__ x, const float* __restrict__ Wg,
                                   const float* __restrict__ bg,
                                   float* __restrict__ interp, float* __restrict__ rowscale) {
  int b = blockIdx.x, t = threadIdx.x;  // 128 blocks x 256
  const float* rp = rowpart + (size_t)b * NBLK;
  float s = 0.f;
  for (int i = t; i < NBLK; i += 256) s += rp[i];
  // gate dot-product: D/4 = 256 float4 chunks, exactly one per thread
  const float4* xr = (const float4*)(x + (size_t)b * D_);
  const float4* wr = (const float4*)Wg;
  float4 xv = xr[t], wv = wr[t];
  float g = xv.x * wv.x + xv.y * wv.y + xv.z * wv.z + xv.w * wv.w;
  for (int o = 32; o > 0; o >>= 1) {
    s += __shfl_down(s, o);
    g += __shfl_down(g, o);
  }
  __shared__ float reds[4], redg[4];
  int lane = t & 63, w = t >> 6;
  if (lane == 0) { reds[w] = s; redg[w] = g; }
  __syncthreads();
  if (t == 0) {
    float tot = redg[0] + redg[1] + redg[2] + redg[3] + bg[0];
    float itp = 1.f / (1.f + __expf(-tot));
    float sum = reds[0] + reds[1] + reds[2] + reds[3];
    interp[b] = itp;
    rowscale[b] = itp / sum;
  }
}

// ---------------- gen gather: out[b,o] = rowscale_b * sum_{v in bucket(o)} elog[b,v] ----
__global__ void gather_gen_kernel(const float* __restrict__ elog, const int* __restrict__ cnt,
                                  const int* __restrict__ vlist,
                                  const float* __restrict__ rowscale, float* __restrict__ out) {
  int o = blockIdx.x * 256 + threadIdx.x;
  int b = blockIdx.y;
  if (o < OUT_V_) {
    int c = cnt[o];
    if (c > CAP) c = CAP;
    const float* lrow = elog + (size_t)b * GEN_V_;
    const int* vl = vlist + (size_t)o * CAP;
    float s = 0.f;
    for (int j = 0; j < c; j++) s += lrow[vl[j]];
    out[(size_t)b * OUT_V_ + o] = s * rowscale[b];
  }
}

// ---------------- overflow cleanup (normally novf==0): atomic adds ------------------
__global__ void ovf_kernel(const int* __restrict__ novf, const int* __restrict__ ovf,
                           const float* __restrict__ elog, const float* __restrict__ rowscale,
                           float* __restrict__ out) {
  int n = novf[0];
  if (n == 0) return;
  int total = n * B_;
  for (int i = blockIdx.x * 256 + threadIdx.x; i < total; i += gridDim.x * 256) {
    int e = i >> 7;          // entry
    int b = i & 127;         // row
    int o = ovf[2 * e];
    int v = ovf[2 * e + 1];
    atomicAdd(&out[(size_t)b * OUT_V_ + o], rowscale[b] * elog[(size_t)b * GEN_V_ + v]);
  }
}

// ---------------- ptr scatter: out[b, i2o[ctx[b,s]]] += (1-interp_b) * alphas[b,s] --
__global__ void scatter_ptr_kernel(const float* __restrict__ alphas, const int* __restrict__ ctx,
                                   const int* __restrict__ i2o, const float* __restrict__ interp,
                                   float* __restrict__ out) {
  int b = blockIdx.x, s = threadIdx.x;  // 512 threads
  float w = 1.f - interp[b];
  int o = i2o[ctx[b * S_ + s]];
  atomicAdd(&out[(size_t)b * OUT_V_ + o], w * alphas[b * S_ + s]);
}

extern "C" void kernel_launch(void* const* d_in, const int* in_sizes, int n_in,
                              void* d_out, int out_size, void* d_ws, size_t ws_size,
                              hipStream_t stream) {
  const float* x      = (const float*)d_in[0];
  const float* alphas = (const float*)d_in[1];
  const float* Wg     = (const float*)d_in[2];
  const float* bg     = (const float*)d_in[3];
  const float* Wgen   = (const float*)d_in[4];
  const float* bgen   = (const float*)d_in[5];
  const int*   ctx    = (const int*)d_in[6];
  const int*   g2o    = (const int*)d_in[7];
  const int*   i2o    = (const int*)d_in[8];
  float* out = (float*)d_out;

  // workspace layout (4B elems):
  // elog[128*50000] | interp[128] | rowscale[128] | rowpart[128*NBLK]
  // | cnt[OUT_V] | novf[1] | vlist[OUT_V*CAP] | ovf[2*GEN_V]
  float* elog      = (float*)d_ws;
  float* interp    = elog + (size_t)B_ * GEN_V_;
  float* rowscale  = interp + B_;
  float* rowpart   = rowscale + B_;
  int*   cnt       = (int*)(rowpart + (size_t)B_ * NBLK);
  int*   novf      = cnt + OUT_V_;
  int*   vlist     = novf + 1;
  int*   ovf       = vlist + (size_t)OUT_V_ * CAP;

  // zero cnt + novf in one contiguous memset
  hipMemsetAsync(cnt, 0, (OUT_V_ + 1) * sizeof(int), stream);

  build_index_kernel<<<(GEN_V_ + 255) / 256, 256, 0, stream>>>(g2o, cnt, vlist, novf, ovf);
  gemm_kernel<<<NBLK, 512, 0, stream>>>(x, Wgen, bgen, elog, rowpart);
  rowsum_gate_kernel<<<B_, 256, 0, stream>>>(rowpart, x, Wg, bg, interp, rowscale);
  gather_gen_kernel<<<dim3((OUT_V_ + 255) / 256, B_), 256, 0, stream>>>(
      elog, cnt, vlist, rowscale, out);
  ovf_kernel<<<64, 256, 0, stream>>>(novf, ovf, elog, rowscale, out);
  scatter_ptr_kernel<<<B_, S_, 0, stream>>>(alphas, ctx, i2o, interp, out);
}

// Round 3
// 397.673 us; speedup vs baseline: 1.5940x; 1.0224x over previous
//
#include <hip/hip_runtime.h>
#include <hip/hip_bf16.h>
#include <cstdint>
#include <cstddef>

#define B_ 128
#define D_ 1024
#define GEN_V_ 50000
#define OUT_V_ 50257
#define S_ 512

#define NTILE 128
#define NBLK 391         // ceil(GEN_V/128)
#define BK 64
#define LD 72            // padded k-stride (shorts); 36-dword row stride
#define CAP 8            // bucket capacity for inverted index (Poisson lambda~1)

typedef __attribute__((ext_vector_type(8))) short bf16x8;
typedef __attribute__((ext_vector_type(8))) unsigned short u16x8;
typedef __attribute__((ext_vector_type(4))) float f32x4;

__device__ __forceinline__ unsigned short f2bf(float f) {
  unsigned u = __float_as_uint(f);
  u += 0x7fffu + ((u >> 16) & 1u);   // RNE
  return (unsigned short)(u >> 16);
}

// ---------------- GEMM + fused exp + row partial sums -----------------------------
// elog[b][v] = exp(x@W_gen + b_gen);  rowpart[row][blk] = sum over this block's cols.
// Block: 512 threads (8 waves, 2(M)x4(N)), tile M=128 x N=128, BK=64.
// Wave tile: 64(M) x 32(N) -> acc[4][2].
__global__ __launch_bounds__(512, 4) void gemm_kernel(
    const float* __restrict__ x, const float* __restrict__ W,
    const float* __restrict__ bgen, float* __restrict__ elog,
    float* __restrict__ rowpart) {
  __shared__ unsigned short sA[B_][LD];      // [m][k] bf16
  __shared__ unsigned short sB[NTILE][LD];   // [n][k] bf16 (k-packed stores: conflict-free)
  __shared__ float srow[B_];
  int tid = threadIdx.x;
  int lane = tid & 63;
  int wv = tid >> 6;            // 0..7
  int wm = wv & 1;              // m half (64)
  int wn = wv >> 1;             // n quarter (32 cols)
  int nbase = blockIdx.x * NTILE;
  int l15 = lane & 15;
  int quad = lane >> 4;
  int koff0 = quad * 8;

  f32x4 acc[4][2];
#pragma unroll
  for (int i = 0; i < 4; i++)
#pragma unroll
    for (int j = 0; j < 2; j++) acc[i][j] = (f32x4){0.f, 0.f, 0.f, 0.f};

  // B staging: thread owns (n = tid&127, kc = tid>>7 in 0..3), 16 k's each
  int bn = tid & 127;
  int kc = tid >> 7;
  bool colv = (nbase + bn) < GEN_V_;
  const float* Wcol = W + (size_t)kc * 16 * GEN_V_ + nbase + bn;

  const float4* xg = (const float4*)x;

  for (int k0 = 0; k0 < D_; k0 += BK) {
    // ---- stage A: x[0:128, k0:+64] fp32 -> bf16, [m][k] (coalesced 256B rows) ----
    int kb4 = k0 >> 2;
#pragma unroll
    for (int i = 0; i < 4; i++) {
      int q = tid + i * 512;          // 0..2047
      int m = q >> 4, c4 = q & 15;    // 16 float4 per 64-k row
      float4 v = xg[(size_t)m * (D_ / 4) + kb4 + c4];
      ushort4 h;
      h.x = f2bf(v.x); h.y = f2bf(v.y); h.z = f2bf(v.z); h.w = f2bf(v.w);
      *(ushort4*)&sA[m][c4 * 4] = h;
    }
    // ---- stage B: W[k0:+64, nbase:+128] -> bf16 [n][k], two 16B k-packed stores ----
    {
      const float* Wp = Wcol + (size_t)k0 * GEN_V_;
      u16x8 h0, h1;
#pragma unroll
      for (int j = 0; j < 8; j++) {
        float w = colv ? Wp[(size_t)j * GEN_V_] : 0.f;
        h0[j] = f2bf(w);
      }
#pragma unroll
      for (int j = 0; j < 8; j++) {
        float w = colv ? Wp[(size_t)(j + 8) * GEN_V_] : 0.f;
        h1[j] = f2bf(w);
      }
      *(u16x8*)&sB[bn][kc * 16] = h0;      // dword stride 36/row: lanes cover 32 banks
      *(u16x8*)&sB[bn][kc * 16 + 8] = h1;
    }
    __syncthreads();
    // ---- MFMA: wave tile 64(M) x 32(N) ----
#pragma unroll
    for (int ks = 0; ks < BK; ks += 32) {
      int koff = ks + koff0;
      bf16x8 bfr[2];
      bfr[0] = *(const bf16x8*)&sB[wn * 32 + l15][koff];
      bfr[1] = *(const bf16x8*)&sB[wn * 32 + 16 + l15][koff];
      bf16x8 af[4];
#pragma unroll
      for (int mt = 0; mt < 4; mt++)
        af[mt] = *(const bf16x8*)&sA[wm * 64 + mt * 16 + l15][koff];
#pragma unroll
      for (int mt = 0; mt < 4; mt++) {
        acc[mt][0] = __builtin_amdgcn_mfma_f32_16x16x32_bf16(af[mt], bfr[0], acc[mt][0], 0, 0, 0);
        acc[mt][1] = __builtin_amdgcn_mfma_f32_16x16x32_bf16(af[mt], bfr[1], acc[mt][1], 0, 0, 0);
      }
    }
    __syncthreads();
  }

  // ---- epilogue: e = exp(acc + bias); store elog; per-row partial sums ----
  if (tid < B_) srow[tid] = 0.f;
  __syncthreads();
  int rquad = quad * 4;
#pragma unroll
  for (int nt = 0; nt < 2; nt++) {
    int cg = nbase + wn * 32 + nt * 16 + l15;
    bool cv = cg < GEN_V_;
    float bgv = cv ? bgen[cg] : 0.f;
#pragma unroll
    for (int mt = 0; mt < 4; mt++) {
      int rb = wm * 64 + mt * 16 + rquad;
#pragma unroll
      for (int r = 0; r < 4; r++) {
        float e = __expf(acc[mt][nt][r] + bgv);   // logits in ±~5: no max-sub needed
        float contrib = cv ? e : 0.f;
        if (cv) elog[(size_t)(rb + r) * GEN_V_ + cg] = e;
        // reduce across the 16 lanes sharing this row (stays within quad)
#pragma unroll
        for (int o = 1; o < 16; o <<= 1) contrib += __shfl_xor(contrib, o);
        if (l15 == 0) atomicAdd(&srow[rb + r], contrib);
      }
    }
  }
  __syncthreads();
  if (tid < B_) rowpart[(size_t)tid * NBLK + blockIdx.x] = srow[tid];
}

// ------------- inverted index of g2o: fixed-cap buckets + overflow list -------------
__global__ void build_index_kernel(const int* __restrict__ g2o, int* __restrict__ cnt,
                                   int* __restrict__ vlist, int* __restrict__ novf,
                                   int* __restrict__ ovf) {
  int v = blockIdx.x * 256 + threadIdx.x;
  if (v < GEN_V_) {
    int o = g2o[v];
    int slot = atomicAdd(&cnt[o], 1);
    if (slot < CAP) {
      vlist[o * CAP + slot] = v;
    } else {
      int i = atomicAdd(novf, 1);
      ovf[2 * i] = o;
      ovf[2 * i + 1] = v;
    }
  }
}

// ------------- rowsum + gate fused: rowscale[b] = sigmoid(x·Wg+bg) / sum_b ---------
__global__ void rowsum_gate_kernel(const float* __restrict__ rowpart,
                                   const float* __restrict__ x, const float* __restrict__ Wg,
                                   const float* __restrict__ bg,
                                   float* __restrict__ interp, float* __restrict__ rowscale) {
  int b = blockIdx.x, t = threadIdx.x;  // 128 blocks x 256
  const float* rp = rowpart + (size_t)b * NBLK;
  float s = 0.f;
  for (int i = t; i < NBLK; i += 256) s += rp[i];
  // gate dot-product: D/4 = 256 float4 chunks, exactly one per thread
  const float4* xr = (const float4*)(x + (size_t)b * D_);
  const float4* wr = (const float4*)Wg;
  float4 xv = xr[t], wv = wr[t];
  float g = xv.x * wv.x + xv.y * wv.y + xv.z * wv.z + xv.w * wv.w;
  for (int o = 32; o > 0; o >>= 1) {
    s += __shfl_down(s, o);
    g += __shfl_down(g, o);
  }
  __shared__ float reds[4], redg[4];
  int lane = t & 63, w = t >> 6;
  if (lane == 0) { reds[w] = s; redg[w] = g; }
  __syncthreads();
  if (t == 0) {
    float tot = redg[0] + redg[1] + redg[2] + redg[3] + bg[0];
    float itp = 1.f / (1.f + __expf(-tot));
    float sum = reds[0] + reds[1] + reds[2] + reds[3];
    interp[b] = itp;
    rowscale[b] = itp / sum;
  }
}

// -------- gen gather: out[b,o] = rowscale_b * sum_{v in bucket(o)} elog[b,v] --------
// XCD b-affinity: block id -> b = (id&7)*16 + ((id>>3)&15), oc = id>>7.
// XCDs take blocks round-robin on id%8, so XCD x owns b in [16x,16x+16): its 16 elog
// rows (3.2 MB) stay resident in that XCD's 4 MB L2 -> no cross-XCD elog re-fetch.
#define GATHER_NB (128 * 197)   // 197 = ceil(OUT_V/256) o-chunks x 128 b
__global__ void gather_gen_kernel(const float* __restrict__ elog, const int* __restrict__ cnt,
                                  const int* __restrict__ vlist,
                                  const float* __restrict__ rowscale, float* __restrict__ out) {
  int id = blockIdx.x;
  int b = (id & 7) * 16 + ((id >> 3) & 15);
  int o = (id >> 7) * 256 + threadIdx.x;
  if (o < OUT_V_) {
    int c = cnt[o];
    if (c > CAP) c = CAP;
    const float* lrow = elog + (size_t)b * GEN_V_;
    const int* vl = vlist + (size_t)o * CAP;
    float s = 0.f;
    for (int j = 0; j < c; j++) s += lrow[vl[j]];
    out[(size_t)b * OUT_V_ + o] = s * rowscale[b];
  }
}

// ---------------- overflow cleanup (normally novf==0): atomic adds ------------------
__global__ void ovf_kernel(const int* __restrict__ novf, const int* __restrict__ ovf,
                           const float* __restrict__ elog, const float* __restrict__ rowscale,
                           float* __restrict__ out) {
  int n = novf[0];
  if (n == 0) return;
  int total = n * B_;
  for (int i = blockIdx.x * 256 + threadIdx.x; i < total; i += gridDim.x * 256) {
    int e = i >> 7;          // entry
    int b = i & 127;         // row
    int o = ovf[2 * e];
    int v = ovf[2 * e + 1];
    atomicAdd(&out[(size_t)b * OUT_V_ + o], rowscale[b] * elog[(size_t)b * GEN_V_ + v]);
  }
}

// ---------------- ptr scatter: out[b, i2o[ctx[b,s]]] += (1-interp_b) * alphas[b,s] --
__global__ void scatter_ptr_kernel(const float* __restrict__ alphas, const int* __restrict__ ctx,
                                   const int* __restrict__ i2o, const float* __restrict__ interp,
                                   float* __restrict__ out) {
  int b = blockIdx.x, s = threadIdx.x;  // 512 threads
  float w = 1.f - interp[b];
  int o = i2o[ctx[b * S_ + s]];
  atomicAdd(&out[(size_t)b * OUT_V_ + o], w * alphas[b * S_ + s]);
}

extern "C" void kernel_launch(void* const* d_in, const int* in_sizes, int n_in,
                              void* d_out, int out_size, void* d_ws, size_t ws_size,
                              hipStream_t stream) {
  const float* x      = (const float*)d_in[0];
  const float* alphas = (const float*)d_in[1];
  const float* Wg     = (const float*)d_in[2];
  const float* bg     = (const float*)d_in[3];
  const float* Wgen   = (const float*)d_in[4];
  const float* bgen   = (const float*)d_in[5];
  const int*   ctx    = (const int*)d_in[6];
  const int*   g2o    = (const int*)d_in[7];
  const int*   i2o    = (const int*)d_in[8];
  float* out = (float*)d_out;

  // workspace layout (4B elems):
  // elog[128*50000] | interp[128] | rowscale[128] | rowpart[128*NBLK]
  // | cnt[OUT_V] | novf[1] | vlist[OUT_V*CAP] | ovf[2*GEN_V]
  float* elog      = (float*)d_ws;
  float* interp    = elog + (size_t)B_ * GEN_V_;
  float* rowscale  = interp + B_;
  float* rowpart   = rowscale + B_;
  int*   cnt       = (int*)(rowpart + (size_t)B_ * NBLK);
  int*   novf      = cnt + OUT_V_;
  int*   vlist     = novf + 1;
  int*   ovf       = vlist + (size_t)OUT_V_ * CAP;

  // zero cnt + novf in one contiguous memset
  hipMemsetAsync(cnt, 0, (OUT_V_ + 1) * sizeof(int), stream);

  build_index_kernel<<<(GEN_V_ + 255) / 256, 256, 0, stream>>>(g2o, cnt, vlist, novf, ovf);
  gemm_kernel<<<NBLK, 512, 0, stream>>>(x, Wgen, bgen, elog, rowpart);
  rowsum_gate_kernel<<<B_, 256, 0, stream>>>(rowpart, x, Wg, bg, interp, rowscale);
  gather_gen_kernel<<<GATHER_NB, 256, 0, stream>>>(elog, cnt, vlist, rowscale, out);
  ovf_kernel<<<64, 256, 0, stream>>>(novf, ovf, elog, rowscale, out);
  scatter_ptr_kernel<<<B_, S_, 0, stream>>>(alphas, ctx, i2o, interp, out);
}

// Round 4
// 382.678 us; speedup vs baseline: 1.6565x; 1.0392x over previous
//
#include <hip/hip_runtime.h>
#include <hip/hip_bf16.h>
#include <cstdint>
#include <cstddef>

#define B_ 128
#define D_ 1024
#define GEN_V_ 50000
#define OUT_V_ 50257
#define S_ 512

#define NTILE 128
#define NBLK 391         // ceil(GEN_V/128)
#define BK 64
#define NSTEP (D_ / BK)  // 16
#define LD 72            // padded k-stride (shorts); 36-dword row stride
#define CAP 8            // bucket capacity for inverted index (Poisson lambda~1)

typedef __attribute__((ext_vector_type(8))) short bf16x8;
typedef __attribute__((ext_vector_type(8))) unsigned short u16x8;
typedef __attribute__((ext_vector_type(4))) float f32x4;

__device__ __forceinline__ unsigned short f2bf(float f) {
  unsigned u = __float_as_uint(f);
  u += 0x7fffu + ((u >> 16) & 1u);   // RNE
  return (unsigned short)(u >> 16);
}

// ---------------- GEMM + fused exp + row partial sums -----------------------------
// elog[b][v] = exp(x@W_gen + b_gen);  rowpart[row][blk] = sum over this block's cols.
// Block: 512 threads (8 waves, 2(M)x4(N)), tile M=128 x N=128, BK=64.
// Software-pipelined (T14): tile t+1's global loads are issued into REGISTERS before
// tile t's MFMA phase; convert+ds_write happen after the read-barrier. Reg-destined
// loads stay in flight across s_barrier (no vmcnt drain), hiding HBM latency.
__global__ __launch_bounds__(512, 4) void gemm_kernel(
    const float* __restrict__ x, const float* __restrict__ W,
    const float* __restrict__ bgen, float* __restrict__ elog,
    float* __restrict__ rowpart) {
  __shared__ unsigned short sA[B_][LD];      // [m][k] bf16
  __shared__ unsigned short sB[NTILE][LD];   // [n][k] bf16 (k-packed stores: conflict-free)
  __shared__ float srow[B_];
  int tid = threadIdx.x;
  int lane = tid & 63;
  int wv = tid >> 6;            // 0..7
  int wm = wv & 1;              // m half (64)
  int wn = wv >> 1;             // n quarter (32 cols)
  int nbase = blockIdx.x * NTILE;
  int l15 = lane & 15;
  int quad = lane >> 4;
  int koff0 = quad * 8;

  f32x4 acc[4][2];
#pragma unroll
  for (int i = 0; i < 4; i++)
#pragma unroll
    for (int j = 0; j < 2; j++) acc[i][j] = (f32x4){0.f, 0.f, 0.f, 0.f};

  // B staging: thread owns (n = tid&127, kc = tid>>7 in 0..3), 16 k's each
  int bn = tid & 127;
  int kc = tid >> 7;
  bool colv = (nbase + bn) < GEN_V_;
  const float* Wcol = W + (size_t)kc * 16 * GEN_V_ + nbase + bn;
  const float4* xg = (const float4*)x;

  // prefetch registers (single set: consumed by WRITE before next LOAD overwrites)
  float wreg[16];
  float4 xreg[4];

  auto LOAD = [&](int k0) {
    const float* Wp = Wcol + (size_t)k0 * GEN_V_;
#pragma unroll
    for (int j = 0; j < 16; j++) wreg[j] = colv ? Wp[(size_t)j * GEN_V_] : 0.f;
    int kb4 = k0 >> 2;
#pragma unroll
    for (int i = 0; i < 4; i++) {
      int q = tid + i * 512;          // 0..2047
      int m = q >> 4, c4 = q & 15;    // 16 float4 per 64-k row
      xreg[i] = xg[(size_t)m * (D_ / 4) + kb4 + c4];
    }
  };
  auto WRITE = [&]() {
#pragma unroll
    for (int i = 0; i < 4; i++) {
      int q = tid + i * 512;
      int m = q >> 4, c4 = q & 15;
      ushort4 h;
      h.x = f2bf(xreg[i].x); h.y = f2bf(xreg[i].y);
      h.z = f2bf(xreg[i].z); h.w = f2bf(xreg[i].w);
      *(ushort4*)&sA[m][c4 * 4] = h;
    }
    u16x8 h0, h1;
#pragma unroll
    for (int j = 0; j < 8; j++) { h0[j] = f2bf(wreg[j]); h1[j] = f2bf(wreg[j + 8]); }
    *(u16x8*)&sB[bn][kc * 16] = h0;      // dword stride 36/row: lanes cover 32 banks
    *(u16x8*)&sB[bn][kc * 16 + 8] = h1;
  };

  // prologue: stage tile 0
  LOAD(0);
  WRITE();
  __syncthreads();

  for (int t = 0; t < NSTEP; ++t) {
    // issue next tile's loads BEFORE compute (latency hides under MFMA phase)
    if (t + 1 < NSTEP) LOAD((t + 1) * BK);
    // ---- MFMA: wave tile 64(M) x 32(N) on LDS tile t ----
#pragma unroll
    for (int ks = 0; ks < BK; ks += 32) {
      int koff = ks + koff0;
      bf16x8 bfr[2];
      bfr[0] = *(const bf16x8*)&sB[wn * 32 + l15][koff];
      bfr[1] = *(const bf16x8*)&sB[wn * 32 + 16 + l15][koff];
      bf16x8 af[4];
#pragma unroll
      for (int mt = 0; mt < 4; mt++)
        af[mt] = *(const bf16x8*)&sA[wm * 64 + mt * 16 + l15][koff];
#pragma unroll
      for (int mt = 0; mt < 4; mt++) {
        acc[mt][0] = __builtin_amdgcn_mfma_f32_16x16x32_bf16(af[mt], bfr[0], acc[mt][0], 0, 0, 0);
        acc[mt][1] = __builtin_amdgcn_mfma_f32_16x16x32_bf16(af[mt], bfr[1], acc[mt][1], 0, 0, 0);
      }
    }
    __syncthreads();                 // all waves done READING tile t
    if (t + 1 < NSTEP) {
      WRITE();                       // waits on loads, converts, ds_writes tile t+1
      __syncthreads();               // tile t+1 visible
    }
  }

  // ---- epilogue: e = exp(acc + bias); store elog; per-row partial sums ----
  if (tid < B_) srow[tid] = 0.f;
  __syncthreads();
  int rquad = quad * 4;
#pragma unroll
  for (int nt = 0; nt < 2; nt++) {
    int cg = nbase + wn * 32 + nt * 16 + l15;
    bool cv = cg < GEN_V_;
    float bgv = cv ? bgen[cg] : 0.f;
#pragma unroll
    for (int mt = 0; mt < 4; mt++) {
      int rb = wm * 64 + mt * 16 + rquad;
#pragma unroll
      for (int r = 0; r < 4; r++) {
        float e = __expf(acc[mt][nt][r] + bgv);   // logits in ±~5: no max-sub needed
        float contrib = cv ? e : 0.f;
        if (cv) elog[(size_t)(rb + r) * GEN_V_ + cg] = e;
        // reduce across the 16 lanes sharing this row (stays within quad)
#pragma unroll
        for (int o = 1; o < 16; o <<= 1) contrib += __shfl_xor(contrib, o);
        if (l15 == 0) atomicAdd(&srow[rb + r], contrib);
      }
    }
  }
  __syncthreads();
  if (tid < B_) rowpart[(size_t)tid * NBLK + blockIdx.x] = srow[tid];
}

// ------------- inverted index of g2o: fixed-cap buckets + overflow list -------------
__global__ void build_index_kernel(const int* __restrict__ g2o, int* __restrict__ cnt,
                                   int* __restrict__ vlist, int* __restrict__ novf,
                                   int* __restrict__ ovf) {
  int v = blockIdx.x * 256 + threadIdx.x;
  if (v < GEN_V_) {
    int o = g2o[v];
    int slot = atomicAdd(&cnt[o], 1);
    if (slot < CAP) {
      vlist[o * CAP + slot] = v;
    } else {
      int i = atomicAdd(novf, 1);
      ovf[2 * i] = o;
      ovf[2 * i + 1] = v;
    }
  }
}

// ------------- rowsum + gate fused: rowscale[b] = sigmoid(x·Wg+bg) / sum_b ---------
__global__ void rowsum_gate_kernel(const float* __restrict__ rowpart,
                                   const float* __restrict__ x, const float* __restrict__ Wg,
                                   const float* __restrict__ bg,
                                   float* __restrict__ interp, float* __restrict__ rowscale) {
  int b = blockIdx.x, t = threadIdx.x;  // 128 blocks x 256
  const float* rp = rowpart + (size_t)b * NBLK;
  float s = 0.f;
  for (int i = t; i < NBLK; i += 256) s += rp[i];
  // gate dot-product: D/4 = 256 float4 chunks, exactly one per thread
  const float4* xr = (const float4*)(x + (size_t)b * D_);
  const float4* wr = (const float4*)Wg;
  float4 xv = xr[t], wv = wr[t];
  float g = xv.x * wv.x + xv.y * wv.y + xv.z * wv.z + xv.w * wv.w;
  for (int o = 32; o > 0; o >>= 1) {
    s += __shfl_down(s, o);
    g += __shfl_down(g, o);
  }
  __shared__ float reds[4], redg[4];
  int lane = t & 63, w = t >> 6;
  if (lane == 0) { reds[w] = s; redg[w] = g; }
  __syncthreads();
  if (t == 0) {
    float tot = redg[0] + redg[1] + redg[2] + redg[3] + bg[0];
    float itp = 1.f / (1.f + __expf(-tot));
    float sum = reds[0] + reds[1] + reds[2] + reds[3];
    interp[b] = itp;
    rowscale[b] = itp / sum;
  }
}

// -------- gen gather: out[b,o] = rowscale_b * sum_{v in bucket(o)} elog[b,v] --------
// XCD b-affinity: block id -> b = (id&7)*16 + ((id>>3)&15), oc = id>>7.
// XCDs take blocks round-robin on id%8, so XCD x owns b in [16x,16x+16): its 16 elog
// rows (3.2 MB) stay resident in that XCD's 4 MB L2 -> no cross-XCD elog re-fetch.
#define GATHER_NB (128 * 197)   // 197 = ceil(OUT_V/256) o-chunks x 128 b
__global__ void gather_gen_kernel(const float* __restrict__ elog, const int* __restrict__ cnt,
                                  const int* __restrict__ vlist,
                                  const float* __restrict__ rowscale, float* __restrict__ out) {
  int id = blockIdx.x;
  int b = (id & 7) * 16 + ((id >> 3) & 15);
  int o = (id >> 7) * 256 + threadIdx.x;
  if (o < OUT_V_) {
    int c = cnt[o];
    if (c > CAP) c = CAP;
    const float* lrow = elog + (size_t)b * GEN_V_;
    const int* vl = vlist + (size_t)o * CAP;
    float s = 0.f;
    for (int j = 0; j < c; j++) s += lrow[vl[j]];
    out[(size_t)b * OUT_V_ + o] = s * rowscale[b];
  }
}

// ---------------- overflow cleanup (normally novf==0): atomic adds ------------------
__global__ void ovf_kernel(const int* __restrict__ novf, const int* __restrict__ ovf,
                           const float* __restrict__ elog, const float* __restrict__ rowscale,
                           float* __restrict__ out) {
  int n = novf[0];
  if (n == 0) return;
  int total = n * B_;
  for (int i = blockIdx.x * 256 + threadIdx.x; i < total; i += gridDim.x * 256) {
    int e = i >> 7;          // entry
    int b = i & 127;         // row
    int o = ovf[2 * e];
    int v = ovf[2 * e + 1];
    atomicAdd(&out[(size_t)b * OUT_V_ + o], rowscale[b] * elog[(size_t)b * GEN_V_ + v]);
  }
}

// ---------------- ptr scatter: out[b, i2o[ctx[b,s]]] += (1-interp_b) * alphas[b,s] --
__global__ void scatter_ptr_kernel(const float* __restrict__ alphas, const int* __restrict__ ctx,
                                   const int* __restrict__ i2o, const float* __restrict__ interp,
                                   float* __restrict__ out) {
  int b = blockIdx.x, s = threadIdx.x;  // 512 threads
  float w = 1.f - interp[b];
  int o = i2o[ctx[b * S_ + s]];
  atomicAdd(&out[(size_t)b * OUT_V_ + o], w * alphas[b * S_ + s]);
}

extern "C" void kernel_launch(void* const* d_in, const int* in_sizes, int n_in,
                              void* d_out, int out_size, void* d_ws, size_t ws_size,
                              hipStream_t stream) {
  const float* x      = (const float*)d_in[0];
  const float* alphas = (const float*)d_in[1];
  const float* Wg     = (const float*)d_in[2];
  const float* bg     = (const float*)d_in[3];
  const float* Wgen   = (const float*)d_in[4];
  const float* bgen   = (const float*)d_in[5];
  const int*   ctx    = (const int*)d_in[6];
  const int*   g2o    = (const int*)d_in[7];
  const int*   i2o    = (const int*)d_in[8];
  float* out = (float*)d_out;

  // workspace layout (4B elems):
  // elog[128*50000] | interp[128] | rowscale[128] | rowpart[128*NBLK]
  // | cnt[OUT_V] | novf[1] | vlist[OUT_V*CAP] | ovf[2*GEN_V]
  float* elog      = (float*)d_ws;
  float* interp    = elog + (size_t)B_ * GEN_V_;
  float* rowscale  = interp + B_;
  float* rowpart   = rowscale + B_;
  int*   cnt       = (int*)(rowpart + (size_t)B_ * NBLK);
  int*   novf      = cnt + OUT_V_;
  int*   vlist     = novf + 1;
  int*   ovf       = vlist + (size_t)OUT_V_ * CAP;

  // zero cnt + novf in one contiguous memset
  hipMemsetAsync(cnt, 0, (OUT_V_ + 1) * sizeof(int), stream);

  build_index_kernel<<<(GEN_V_ + 255) / 256, 256, 0, stream>>>(g2o, cnt, vlist, novf, ovf);
  gemm_kernel<<<NBLK, 512, 0, stream>>>(x, Wgen, bgen, elog, rowpart);
  rowsum_gate_kernel<<<B_, 256, 0, stream>>>(rowpart, x, Wg, bg, interp, rowscale);
  gather_gen_kernel<<<GATHER_NB, 256, 0, stream>>>(elog, cnt, vlist, rowscale, out);
  ovf_kernel<<<64, 256, 0, stream>>>(novf, ovf, elog, rowscale, out);
  scatter_ptr_kernel<<<B_, S_, 0, stream>>>(alphas, ctx, i2o, interp, out);
}